// Round 3
// baseline (277.442 us; speedup 1.0000x reference)
//
#include <hip/hip_runtime.h>

// out[s, :] = W_tok[x[s], :] + b_tok[:] + W_pos[(S-1)-s, :] + b_pos[:]
// S = 8192, D = 1024 floats (= 256 vec4 chunks), all fp32.
//
// Memory-bound: ~96 MB HBM traffic (32 MB W_tok gather + 32 MB W_pos stream
// + 32 MB out stream) -> ~15-17 us floor at achievable mixed-traffic BW.
//
// R4: A/B the nontemporal flags (inherited untested from the prior session).
//  - Stores: REGULAR (write-back through TCC). The harness fills sustain
//    83% of peak with regular stores; nt (no-allocate/evict-first) may
//    bypass TCC write-combining. Out's 32 MB in L2 evicts nothing of
//    value (no data is reused within an iteration).
//  - W_tok gather: REGULAR. ~8% of rows are intra-batch duplicates
//    (~2.5 MB) that L2 can serve; nt forfeited those hits for nothing.
//  - W_pos: still NT -- pure once-through stream, no-allocate is right.
// Kept from R3 (verified +6.6 us): bias loads first in vmcnt order,
// per-row p/a interleave so stores overlap the gather tail via partial
// vmcnt waits; ROWS=4 + __launch_bounds__(256, 8) for 32 waves/CU.
typedef float v4f __attribute__((ext_vector_type(4)));

#define ROWS 4

__global__ void __launch_bounds__(256, 8)
embedding_kernel(const int* __restrict__ x,
                 const v4f* __restrict__ W_tok,
                 const v4f* __restrict__ b_tok,
                 const v4f* __restrict__ W_pos,
                 const v4f* __restrict__ b_pos,
                 v4f* __restrict__ out,
                 int S) {
    const int d = threadIdx.x;                 // vec4 chunk 0..255 within a row
    const int s0 = blockIdx.x * ROWS;

    // Biases first: L2-hot, return quickly, early in vmcnt order.
    const v4f bt = b_tok[d];
    const v4f bp = b_pos[d];

    // 4 token ids in one scalar dwordx4 load (block-uniform address ->
    // scalar cache, lgkmcnt not vmcnt).
    const int4 t = *reinterpret_cast<const int4*>(x + s0);
    const int tok[ROWS] = {t.x, t.y, t.z, t.w};

    // Streamed + gathered loads, interleaved per row so completion order
    // matches consumption order: p0,a0,p1,a1,...
    v4f p[ROWS], a[ROWS];
#pragma unroll
    for (int r = 0; r < ROWS; ++r) {
        p[r] = __builtin_nontemporal_load(
            &W_pos[(size_t)(S - 1 - (s0 + r)) * 256 + d]);
        a[r] = W_tok[(size_t)tok[r] * 256 + d];
    }

    const v4f bsum = bt + bp;

    // Consume rows in issue order: row r's add only needs vmcnt drained
    // through a[r] -> partial waits, stores overlap remaining loads.
#pragma unroll
    for (int r = 0; r < ROWS; ++r) {
        out[(size_t)(s0 + r) * 256 + d] = a[r] + p[r] + bsum;
    }
}

extern "C" void kernel_launch(void* const* d_in, const int* in_sizes, int n_in,
                              void* d_out, int out_size, void* d_ws, size_t ws_size,
                              hipStream_t stream) {
    const int* x     = (const int*)d_in[0];        // [8192] int32
    const v4f* W_tok = (const v4f*)d_in[1];        // [50257, 1024] f32
    const v4f* b_tok = (const v4f*)d_in[2];        // [1024] f32
    const v4f* W_pos = (const v4f*)d_in[3];        // [8192, 1024] f32
    const v4f* b_pos = (const v4f*)d_in[4];        // [1024] f32
    v4f* out = (v4f*)d_out;                        // [8192, 1024] f32

    const int S = in_sizes[0];                     // 8192

    embedding_kernel<<<S / ROWS, 256, 0, stream>>>(
        x, W_tok, b_tok, W_pos, b_pos, out, S);
}

// Round 4
// 270.676 us; speedup vs baseline: 1.0250x; 1.0250x over previous
//
#include <hip/hip_runtime.h>

// out[s, :] = W_tok[x[s], :] + b_tok[:] + W_pos[(S-1)-s, :] + b_pos[:]
// S = 8192, D = 1024 floats (= 256 vec4 chunks), all fp32.
//
// Memory-bound: ~96 MB HBM traffic (32 MB W_tok gather + 32 MB W_pos stream
// + 32 MB out stream) -> ~15-17 us floor at achievable mixed-traffic BW.
//
// R5 = revert to R3 (verified best, 269.5 us total / ~23.5 us kernel).
// R4's A/B proved the nontemporal flags are WORTH ~5 us:
//  - nt stores: evict-first, so out's 32 MB doesn't sit dirty in L2 and
//    force evictions to interleave with the demand read stream.
//  - nt gather: don't allocate 30 MB of never-reused W_tok lines.
//    (The ~8% intra-batch duplicate rows turn out not to matter.)
//  - nt W_pos: pure once-through stream.
// Kept structure (each verified in earlier rounds):
//  - Biases loaded FIRST in vmcnt order; rows consumed in issue order so
//    the compiler emits partial vmcnt waits and stores overlap the
//    gather tail (R3: +6.6 us vs bias-last full-drain).
//  - Token ids as one block-uniform int4 -> s_load_dwordx4 (lgkmcnt).
//  - ROWS=4 + __launch_bounds__(256, 8): 8 waves/SIMD = 32/CU cap,
//    256 KB of wave-loads in flight per CU >> Little's-law need.
typedef float v4f __attribute__((ext_vector_type(4)));

#define ROWS 4

__global__ void __launch_bounds__(256, 8)
embedding_kernel(const int* __restrict__ x,
                 const v4f* __restrict__ W_tok,
                 const v4f* __restrict__ b_tok,
                 const v4f* __restrict__ W_pos,
                 const v4f* __restrict__ b_pos,
                 v4f* __restrict__ out,
                 int S) {
    const int d = threadIdx.x;                 // vec4 chunk 0..255 within a row
    const int s0 = blockIdx.x * ROWS;

    // Biases first: L2-hot, return quickly, early in vmcnt order.
    const v4f bt = b_tok[d];
    const v4f bp = b_pos[d];

    // 4 token ids in one scalar dwordx4 load (block-uniform address ->
    // scalar cache, lgkmcnt not vmcnt).
    const int4 t = *reinterpret_cast<const int4*>(x + s0);
    const int tok[ROWS] = {t.x, t.y, t.z, t.w};

    // Streamed + gathered loads, interleaved per row so completion order
    // matches consumption order: p0,a0,p1,a1,...
    v4f p[ROWS], a[ROWS];
#pragma unroll
    for (int r = 0; r < ROWS; ++r) {
        p[r] = __builtin_nontemporal_load(
            &W_pos[(size_t)(S - 1 - (s0 + r)) * 256 + d]);
        a[r] = __builtin_nontemporal_load(
            &W_tok[(size_t)tok[r] * 256 + d]);
    }

    const v4f bsum = bt + bp;

    // Consume rows in issue order: row r's add only needs vmcnt drained
    // through a[r] -> partial waits, stores overlap remaining loads.
#pragma unroll
    for (int r = 0; r < ROWS; ++r) {
        v4f o = a[r] + p[r] + bsum;
        __builtin_nontemporal_store(o, &out[(size_t)(s0 + r) * 256 + d]);
    }
}

extern "C" void kernel_launch(void* const* d_in, const int* in_sizes, int n_in,
                              void* d_out, int out_size, void* d_ws, size_t ws_size,
                              hipStream_t stream) {
    const int* x     = (const int*)d_in[0];        // [8192] int32
    const v4f* W_tok = (const v4f*)d_in[1];        // [50257, 1024] f32
    const v4f* b_tok = (const v4f*)d_in[2];        // [1024] f32
    const v4f* W_pos = (const v4f*)d_in[3];        // [8192, 1024] f32
    const v4f* b_pos = (const v4f*)d_in[4];        // [1024] f32
    v4f* out = (v4f*)d_out;                        // [8192, 1024] f32

    const int S = in_sizes[0];                     // 8192

    embedding_kernel<<<S / ROWS, 256, 0, stream>>>(
        x, W_tok, b_tok, W_pos, b_pos, out, S);
}